// Round 1
// baseline (89495.374 us; speedup 1.0000x reference)
//
#include <hip/hip_runtime.h>

#define SEQ 32768
#define ISZ 256
#define HSZ 512
#define OSZ 256
#define GWG 8          // workgroups in recurrence (64 rows each)
#define RTHREADS 512   // 8 waves per WG

// ---------------------------------------------------------------------------
// Generic tiled GEMM:  C[M,N] = A[M,K] @ W[N,K]^T + bias[N]
// block = 256 threads, tile 64x64, TK=32, 4x4 outputs per thread.
// ---------------------------------------------------------------------------
__global__ __launch_bounds__(256) void gemm_bt_bias(
    const float* __restrict__ A, const float* __restrict__ W,
    const float* __restrict__ bias, float* __restrict__ C,
    int M, int N, int K)
{
  // stride 68 words: keeps 16B alignment for b128 reads in the compute phase
  __shared__ float As[32][68];
  __shared__ float Bs[32][68];
  const int tx = threadIdx.x;
  const int tn = tx & 15, tm = tx >> 4;
  const int m0 = blockIdx.x * 64, n0 = blockIdx.y * 64;
  const int kl = tx & 31;   // k within tile
  const int rl = tx >> 5;   // row 0..7
  float acc[4][4] = {};

  for (int kt = 0; kt < K; kt += 32) {
#pragma unroll
    for (int i = 0; i < 8; ++i) {
      int m = rl + i * 8;
      As[kl][m] = A[(size_t)(m0 + m) * K + kt + kl];
      Bs[kl][m] = W[(size_t)(n0 + m) * K + kt + kl];
    }
    __syncthreads();
#pragma unroll
    for (int k = 0; k < 32; ++k) {
      float a[4], b[4];
#pragma unroll
      for (int i = 0; i < 4; ++i) a[i] = As[k][tm * 4 + i];
#pragma unroll
      for (int j = 0; j < 4; ++j) b[j] = Bs[k][tn * 4 + j];
#pragma unroll
      for (int i = 0; i < 4; ++i)
#pragma unroll
        for (int j = 0; j < 4; ++j)
          acc[i][j] = fmaf(a[i], b[j], acc[i][j]);
    }
    __syncthreads();
  }
#pragma unroll
  for (int i = 0; i < 4; ++i) {
    int m = m0 + tm * 4 + i;
#pragma unroll
    for (int j = 0; j < 4; ++j) {
      int n = n0 + tn * 4 + j;
      C[(size_t)m * N + n] = acc[i][j] + bias[n];
    }
  }
}

// ---------------------------------------------------------------------------
// Persistent recurrence: h_{t+1} = tanh(P[t] + Wh @ h_t)
// 8 WGs x 512 threads. WG g owns rows [64g, 64g+64). Wave w handles k-chunk
// [64w, 64w+64) — which is exactly WG w's published slice, so each wave
// spins on a single per-step flag. Weights live in 64 VGPRs per lane.
// Cross-WG h exchange: release(flag)/acquire(spin) at agent scope.
// ---------------------------------------------------------------------------
__global__ __launch_bounds__(RTHREADS) void rnn_recur(
    const float* __restrict__ P,     // [SEQ][HSZ]  (Wx@x_t + bh)
    const float* __restrict__ Wh,    // [HSZ][HSZ]
    float* __restrict__ h_hist,      // [SEQ+1][HSZ], row 0 pre-zeroed
    int* __restrict__ flags)         // [(SEQ+1)*GWG], pre-zeroed
{
  const int g = blockIdx.x;
  const int tid = threadIdx.x;
  const int w = tid >> 6;          // wave index = k-chunk index
  const int l = tid & 63;          // lane = row within WG slice
  const int row = (g << 6) + l;
  const int kbase = w << 6;

  // Load this lane's 64 weights: Wh[row][kbase + j]  (contiguous -> dwordx4s)
  float wreg[64];
#pragma unroll
  for (int j = 0; j < 64; ++j)
    wreg[j] = Wh[(size_t)row * HSZ + kbase + j];

  __shared__ float part[2][8][64];   // double-buffered partials -> 1 barrier/step

  for (int t = 0; t < SEQ; ++t) {
    const int buf = t & 1;

    // Prefetch this step's P slice before spinning (hides HBM latency).
    float pv = 0.f;
    if (w == 0) pv = P[(size_t)t * HSZ + (g << 6) + l];

    if (t > 0) {
      if (l == 0) {
        while (__hip_atomic_load(&flags[t * GWG + w], __ATOMIC_RELAXED,
                                 __HIP_MEMORY_SCOPE_AGENT) == 0) { }
      }
      __builtin_amdgcn_fence(__ATOMIC_ACQUIRE, "agent");
    }

    // Coalesced load of this wave's h chunk (lane l -> element l).
    float vh = h_hist[(size_t)t * HSZ + kbase + l];

    // Partial dot: broadcast h[j] across the wave via readlane.
    float acc = 0.f;
#pragma unroll
    for (int j = 0; j < 64; ++j) {
      float hj = __uint_as_float(
          __builtin_amdgcn_readlane(__float_as_uint(vh), j));
      acc = fmaf(wreg[j], hj, acc);
    }
    part[buf][w][l] = acc;
    __syncthreads();

    if (w == 0) {
      float s = 0.f;
#pragma unroll
      for (int q = 0; q < 8; ++q) s += part[buf][q][l];
      float xv = s + pv;
      // fast tanh: 1 - 2/(e^{2x}+1), clamped (exact to ~1e-6; tanh saturated
      // past |x|=15 at fp32 anyway)
      xv = fminf(fmaxf(xv, -15.f), 15.f);
      float e = __expf(2.f * xv);
      float hn = 1.f - 2.f / (e + 1.f);
      h_hist[(size_t)(t + 1) * HSZ + (g << 6) + l] = hn;
      if (l == 0) {
        __hip_atomic_store(&flags[(t + 1) * GWG + g], 1, __ATOMIC_RELEASE,
                           __HIP_MEMORY_SCOPE_AGENT);
      }
    }
    // No trailing barrier needed: next step writes part[buf^1]; a wave can
    // only pass the NEXT barrier after wave 0 finished this reduce.
  }
}

// ---------------------------------------------------------------------------
extern "C" void kernel_launch(void* const* d_in, const int* in_sizes, int n_in,
                              void* d_out, int out_size, void* d_ws, size_t ws_size,
                              hipStream_t stream) {
  const float* x  = (const float*)d_in[0];  // [SEQ][ISZ]
  const float* Wx = (const float*)d_in[1];  // [HSZ][ISZ]
  const float* Wh = (const float*)d_in[2];  // [HSZ][HSZ]
  const float* Wy = (const float*)d_in[3];  // [OSZ][HSZ]
  const float* bh = (const float*)d_in[4];  // [HSZ]
  const float* by = (const float*)d_in[5];  // [OSZ]
  float* out = (float*)d_out;               // [SEQ][OSZ]

  // Workspace layout (ws re-poisoned every call -> re-init what we rely on):
  float* P      = (float*)d_ws;                           // SEQ*HSZ        (64 MB)
  float* h_hist = P + (size_t)SEQ * HSZ;                  // (SEQ+1)*HSZ    (64 MB)
  int*   flags  = (int*)(h_hist + (size_t)(SEQ + 1) * HSZ); // (SEQ+1)*GWG  (1 MB)

  hipMemsetAsync(h_hist, 0, HSZ * sizeof(float), stream);                  // h_0 = 0
  hipMemsetAsync(flags, 0, (size_t)(SEQ + 1) * GWG * sizeof(int), stream); // no flag set

  // Phase 1: P = x @ Wx^T + bh
  gemm_bt_bias<<<dim3(SEQ / 64, HSZ / 64), dim3(256), 0, stream>>>(
      x, Wx, bh, P, SEQ, HSZ, ISZ);

  // Phase 2: sequential recurrence (persistent, 8 co-resident WGs)
  rnn_recur<<<dim3(GWG), dim3(RTHREADS), 0, stream>>>(P, Wh, h_hist, flags);

  // Phase 3: y = h_hist[1..] @ Wy^T + by
  gemm_bt_bias<<<dim3(SEQ / 64, OSZ / 64), dim3(256), 0, stream>>>(
      h_hist + HSZ, Wy, by, out, SEQ, OSZ, HSZ);
}